// Round 18
// baseline (117.197 us; speedup 1.0000x reference)
//
#include <hip/hip_runtime.h>
#include <hip/hip_bf16.h>
#include <cstdint>

// MultiHeadAttention: out = ( softmax(causal((X Wq^T)(X Wk^T)^T / 8)) (X Wv^T) ) Wo^T
// B=2, S=2048, D_MODEL=1024, H=16, D_HEAD=64. All MFMA bf16, accum fp32.
//
// Round-18: GEMM staging/fragment-path rework (R17 counters: qkv 55us at
// MfmaUtil 17.5%, 4.7M bank conflicts, LDS 48KB -> 3 blocks/CU).
//  (a) A fp32 -> bf16 at STAGE time (reg-staged global_load + cvt_pk +
//      ds_write_b64, split around the MFMA phase). Halves A fragment reads,
//      removes 16 cvt_pk from the read path, LDS 48->32KB (4-5 blocks/CU).
//  (b) chunk-XOR swizzle on ALL bf16 LDS tiles (B everywhere + out_proj A)
//      via pre-swizzled gload source + g^((r16>>1)&3) reads — the linear
//      [row][32u16] layout was an 8-way bank conflict on fragment reads.
// attn (R17 fixed-shift softmax) and cvt unchanged.
//
// Workspace layout (64 MB):
//  [0,8M)    Qp  bf16 [16][4096][64]  per-head packed, pre-scaled by log2e/8
//  [8,16M)   Kp  bf16 [16][4096][64]  per-head packed
//  [16,24M)  Vt  bf16 [1024][4096]    V transposed (row = h*64+d, col = token)
//  [24,32M)  Ctx bf16 [4096][1024]
//  [56,64M)  Wq/Wk/Wv/Wo bf16 weights

typedef unsigned short u16;
typedef u16 u16x4 __attribute__((ext_vector_type(4)));
typedef u16 u16x8 __attribute__((ext_vector_type(8)));
typedef unsigned u32x2 __attribute__((ext_vector_type(2)));
typedef __bf16 bf16x8 __attribute__((ext_vector_type(8)));
typedef float f32x4 __attribute__((ext_vector_type(4)));

#define S_LEN 2048
#define DM 1024
#define NH 16
#define DH 64
#define BATCH 2
#define MTOT (BATCH*S_LEN)   // 4096

__device__ __forceinline__ u16 f2bf(float f) {
  union { float f; unsigned u; } v; v.f = f;
  unsigned r = v.u + 0x7FFFu + ((v.u >> 16) & 1u);   // RNE
  return (u16)(r >> 16);
}

__device__ __forceinline__ f32x4 mfma16(u16x8 a, u16x8 b, f32x4 c) {
  return __builtin_amdgcn_mfma_f32_16x16x32_bf16(
      __builtin_bit_cast(bf16x8, a), __builtin_bit_cast(bf16x8, b), c, 0, 0, 0);
}
__device__ __forceinline__ unsigned cvtpk_bf16(float lo, float hi) {
  unsigned r;
  asm("v_cvt_pk_bf16_f32 %0, %1, %2" : "=v"(r) : "v"(lo), "v"(hi));
  return r;
}
// async global -> LDS, 16B per lane; LDS dest = wave-uniform base + lane*16
__device__ __forceinline__ void gload16(const u16* g, u16* l) {
  __builtin_amdgcn_global_load_lds(
      (const __attribute__((address_space(1))) unsigned int*)g,
      (__attribute__((address_space(3))) unsigned int*)l, 16, 0, 0);
}

// ---------------------------------------------------------------- fp32->bf16
// Weights only (each weight is read 32x by its GEMM -> pre-convert pays;
// X tensors are read once -> consumed fp32 directly by the qkv GEMM).
__global__ __launch_bounds__(256) void cvt_kernel(
    const float* __restrict__ s0, const float* __restrict__ s1,
    const float* __restrict__ s2, const float* __restrict__ s3,
    u16* __restrict__ d0, u16* __restrict__ d1,
    u16* __restrict__ d2, u16* __restrict__ d3) {
  const int y = blockIdx.y;
  const float* s = (y == 0) ? s0 : (y == 1) ? s1 : (y == 2) ? s2 : s3;
  u16* d       = (y == 0) ? d0 : (y == 1) ? d1 : (y == 2) ? d2 : d3;
  int i = (blockIdx.x * 256 + threadIdx.x) * 4;
  f32x4 v = *(const f32x4*)&s[i];
  u16x4 o;
  o[0] = f2bf(v[0]); o[1] = f2bf(v[1]); o[2] = f2bf(v[2]); o[3] = f2bf(v[3]);
  *(u16x4*)&d[i] = o;
}

// ---------------------------------------------------------------- GEMM C=A*B^T
// 128x128 tile, BK=32, 4 waves (2x2), 4x4 16x16x32 MFMA.
// Double-buffered LDS, ONE barrier per K-step. Each 16KB buffer:
// [A bf16 128x32][B bf16 128x32], both chunk-XOR-swizzled:
// LDS(row, c16) = G(row, c16 ^ ((row>>1)&3)); fragment reads use the same
// XOR (rows in a fragment differ only in r16 -> swizzle = g ^ ((r16>>1)&3),
// even/odd rows split banks, 2-way residual = free).
// AF32: A arrives fp32; staged via reg (global_load f32x4 -> cvt_pk ->
// ds_write_b64) issued split around the MFMA phase. Race-free: writes to
// buf^1 are issued only after the barrier that retired all buf^1 reads,
// and complete before the next barrier (lgkm drain).
#define BM 128
#define BN 128
#define BKK 32

template<int MODE, bool AF32>
__device__ __forceinline__ void gemm_core(const void* __restrict__ Av,
                                          const u16* __restrict__ Bw,
                                          void* __restrict__ Cv,
                                          int K, float scale,
                                          int bx, int by, u16* smem) {
  const u16* A16 = (const u16*)Av;
  const float* A32 = (const float*)Av;
  const int tid  = threadIdx.x;
  const int lane = tid & 63, w = tid >> 6;
  const int g = lane >> 4, r16 = lane & 15;
  const int wm = w >> 1, wn = w & 1;
  const int rowBase = by * BM;
  const int colBase = bx * BN;
  f32x4 acc[4][4] = {};

  // B staging: gload_lds, source chunk pre-swizzled
  const int srowB = lane >> 2;                            // 0..15
  const int swzB  = ((lane & 3) ^ ((lane >> 3) & 3)) * 8; // src chunk * 8 u16
  const u16* gB[2]; int oB[2];
#pragma unroll
  for (int j = 0; j < 2; j++) {
    const int c = w * 2 + j;
    gB[j] = &Bw[(size_t)(colBase + c * 16 + srowB) * K + swzB];
    oB[j] = c * 512;
  }
  // A staging
  const u16* gA16[2]; int oA16[2];          // bf16 path (gload_lds, swz src)
  const float* gA32[4]; int oAw[4];         // fp32 path (reg-staged cvt)
  if constexpr (AF32) {
    const int arow0 = tid >> 3;             // 0..31 (pass p adds p*32)
    const int ac4   = tid & 7;              // 4-float group within the row
#pragma unroll
    for (int p = 0; p < 4; p++) {
      const int row = p * 32 + arow0;
      gA32[p] = &A32[(size_t)(rowBase + row) * K + ac4 * 4];
      oAw[p]  = row * 32 + (((ac4 >> 1) ^ ((row >> 1) & 3)) * 8) + (ac4 & 1) * 4;
    }
  } else {
#pragma unroll
    for (int j = 0; j < 2; j++) {
      const int c = w * 2 + j;
      gA16[j] = &A16[(size_t)(rowBase + c * 16 + srowB) * K + swzB];
      oA16[j] = c * 512;
    }
  }

  const int NT = K / BKK;
  // prologue: stage tile 0 into buf 0
  {
#pragma unroll
    for (int j = 0; j < 2; j++) gload16(gB[j], smem + 4096 + oB[j]);
    if constexpr (AF32) {
#pragma unroll
      for (int p = 0; p < 4; p++) {
        f32x4 av = *(const f32x4*)gA32[p];
        u32x2 pw = {cvtpk_bf16(av[0], av[1]), cvtpk_bf16(av[2], av[3])};
        *(u32x2*)&smem[oAw[p]] = pw;
      }
    } else {
#pragma unroll
      for (int j = 0; j < 2; j++) gload16(gA16[j], smem + oA16[j]);
    }
  }
  const int rswz = (r16 >> 1) & 3;
  int cur = 0;
  for (int t = 0; t < NT; ++t) {
    __syncthreads();               // stage(t) landed; buf^1 reads (t-1) done
    f32x4 av[4];
    const bool pf = (t + 1 < NT);
    if (pf) {                      // issue next-tile loads (drain: NEXT barrier)
      const int k0n = (t + 1) * BKK;
      u16* nbase = smem + (cur ^ 1) * 8192;
      if constexpr (AF32) {
#pragma unroll
        for (int p = 0; p < 4; p++) av[p] = *(const f32x4*)(gA32[p] + k0n);
      } else {
#pragma unroll
        for (int j = 0; j < 2; j++) gload16(gA16[j] + k0n, nbase + oA16[j]);
      }
#pragma unroll
      for (int j = 0; j < 2; j++) gload16(gB[j] + k0n, nbase + 4096 + oB[j]);
    }
    u16* As = smem + cur * 8192;
    u16* Bs = As + 4096;
    u16x8 af[4], bfv[4];
#pragma unroll
    for (int i = 0; i < 4; i++)
      af[i]  = *(const u16x8*)&As[(wm*64 + i*16 + r16) * 32 + ((g ^ rswz) * 8)];
#pragma unroll
    for (int j = 0; j < 4; j++)
      bfv[j] = *(const u16x8*)&Bs[(wn*64 + j*16 + r16) * 32 + ((g ^ rswz) * 8)];
    __builtin_amdgcn_s_setprio(1);
#pragma unroll
    for (int i = 0; i < 4; i++)
#pragma unroll
      for (int j = 0; j < 4; j++) acc[i][j] = mfma16(af[i], bfv[j], acc[i][j]);
    __builtin_amdgcn_s_setprio(0);
    if (AF32 && pf) {              // write-late: lands before next barrier
      u16* nbase = smem + (cur ^ 1) * 8192;
#pragma unroll
      for (int p = 0; p < 4; p++) {
        u32x2 pw = {cvtpk_bf16(av[p][0], av[p][1]), cvtpk_bf16(av[p][2], av[p][3])};
        *(u32x2*)&nbase[oAw[p]] = pw;
      }
    }
    cur ^= 1;
  }
  // C/D layout: col = lane&15, row = 4*(lane>>4)+reg
#pragma unroll
  for (int i = 0; i < 4; i++) {
#pragma unroll
    for (int j = 0; j < 4; j++) {
      int row = rowBase + wm*64 + i*16 + 4*g;
      int col = colBase + wn*64 + j*16 + r16;
      if (MODE == 0) {
        u16* O = (u16*)Cv;
        int head = col >> 6, d = col & 63;
#pragma unroll
        for (int r = 0; r < 4; r++)
          O[((size_t)head * MTOT + row + r) * DH + d] = f2bf(acc[i][j][r] * scale);
      } else if (MODE == 1) {
        u16x4 o;
#pragma unroll
        for (int r = 0; r < 4; r++) o[r] = f2bf(acc[i][j][r]);
        *(u16x4*)&((u16*)Cv)[(size_t)col * MTOT + row] = o;
      } else {
#pragma unroll
        for (int r = 0; r < 4; r++)
          ((float*)Cv)[(size_t)(row + r) * DM + col] = acc[i][j][r];
      }
    }
  }
}

// panel-locality remap: XCD x (dispatch = flat%8) owns row-panels x*4..x*4+3
// and ALL 8 columns of each -> every A panel fetched by exactly one XCD;
// per-XCD set = 2MB A(fp32) + 2MB W = L2-resident.
__device__ __forceinline__ void gemm_remap(int& bx, int& by) {
  const int flat = blockIdx.x + 8 * blockIdx.y;   // 0..255
  const int xcd = flat & 7, i = flat >> 3;        // i 0..31
  bx = i & 7;
  by = xcd * 4 + (i >> 3);
}

__global__ __launch_bounds__(256) void qkv_proj_kernel(
    const float* __restrict__ Xq, const float* __restrict__ Xk, const float* __restrict__ Xv,
    const u16* __restrict__ Wq, const u16* __restrict__ Wk, const u16* __restrict__ Wv,
    u16* __restrict__ Qp, u16* __restrict__ Kp, u16* __restrict__ Vt) {
  __shared__ u16 smem[16384];   // 32KB = 2 x (8KB A-bf16 + 8KB B)
  int bx, by; gemm_remap(bx, by);
  const int z = blockIdx.z;
  // Q pre-scaled by (1/sqrt(64)) * log2(e) -> softmax in exp2 domain
  if (z == 0)      gemm_core<0, true>(Xq, Wq, Qp, DM, 0.125f * 1.44269504f, bx, by, smem);
  else if (z == 1) gemm_core<0, true>(Xk, Wk, Kp, DM, 1.0f, bx, by, smem);
  else             gemm_core<1, true>(Xv, Wv, Vt, DM, 1.0f, bx, by, smem);
}

__global__ __launch_bounds__(256) void out_proj_kernel(
    const u16* __restrict__ Ctx, const u16* __restrict__ Wo, float* __restrict__ Out) {
  __shared__ u16 smem[16384];   // 32KB
  int bx, by; gemm_remap(bx, by);
  gemm_core<2, false>(Ctx, Wo, Out, DM, 1.0f, bx, by, smem);
}

// ---------------------------------------------------------------- flash attn
// R9 structure + R17 fixed-shift softmax: 16 q-rows/wave, block = 64 q x
// 4 waves sharing dbuf-staged K/V LDS (32KB) + per-wave 2KB swizzled P
// buffer = 40KB. 1024 blocks, ntb = qc+1 uniform. Swapped QK^T (lane owns
// q-col), S accumulator INIT = -16 (fixed softmax shift, no max tracking),
// exp2 direct, l via mfma(P, ones) row-indexed. T5 setprio, chunk-XOR
// swizzle via pre-swizzled gload source.

#define STAGE(B, T)                                                            \
  {                                                                            \
    const int kv0_ = (T) * 64;                                                 \
    _Pragma("unroll")                                                          \
    for (int j = 0; j < 2; j++) {                                              \
      const int rb = wv * 16 + j * 8;                                          \
      gload16(&Kbase[(size_t)(kv0_ + rb + srow) * DH + sc16 * 8],              \
              &Kl[B][rb * 64]);                                                \
      gload16(&Vbase[(size_t)(rb + srow) * MTOT + kv0_ + sc16 * 8],            \
              &Vl[B][rb * 64]);                                                \
    }                                                                          \
  }

#define TILE_BODY(BUF, T)                                                      \
  {                                                                            \
    const int kv0 = (T) * 64;                                                  \
    const f32x4 minit = {-16.f, -16.f, -16.f, -16.f};                          \
    f32x4 s[4] = {minit, minit, minit, minit};   /* C-in = fixed shift */      \
    __builtin_amdgcn_s_setprio(1);                                             \
    _Pragma("unroll")                                                          \
    for (int f = 0; f < 4; f++) {                                              \
      _Pragma("unroll")                                                        \
      for (int ds = 0; ds < 2; ds++) {                                         \
        u16x8 kf = *(const u16x8*)&Kl[BUF][(f * 16 + q16) * 64 +               \
                                           ((ds * 4 + g) ^ qx7) * 8];          \
        s[f] = mfma16(kf, qf[ds], s[f]);                                       \
      }                                                                        \
    }                                                                          \
    __builtin_amdgcn_s_setprio(0);                                             \
    if ((T) == ntb - 1) {      /* only last tile crosses the diagonal */       \
      const int qg = qb16 + q16;                                               \
      _Pragma("unroll")                                                        \
      for (int f = 0; f < 4; f++)                                              \
        _Pragma("unroll")                                                      \
        for (int r = 0; r < 4; r++)                                            \
          if (kv0 + f * 16 + 4 * g + r > qg) s[f][r] = -1e30f;                 \
    }                                                                          \
    _Pragma("unroll")                                                          \
    for (int f = 0; f < 4; f++)                                                \
      _Pragma("unroll")                                                        \
      for (int r = 0; r < 4; r++) s[f][r] = exp2f(s[f][r]);                    \
    /* P (16q x 64kv) -> per-wave swizzled LDS, then read as A-frags */        \
    _Pragma("unroll")                                                          \
    for (int f = 0; f < 4; f++) {                                              \
      const int cidx = (((2 * f + (g >> 1)) ^ qx7) * 8) + 4 * (g & 1);         \
      u32x2 pw = {cvtpk_bf16(s[f][0], s[f][1]), cvtpk_bf16(s[f][2], s[f][3])}; \
      *(u32x2*)&P16[q16 * 64 + cidx] = pw;                                     \
    }                                                                          \
    asm volatile("s_waitcnt lgkmcnt(0)" ::: "memory");                         \
    __builtin_amdgcn_sched_barrier(0);                                         \
    u16x8 pa0 = *(const u16x8*)&P16[q16 * 64 + ((g)     ^ qx7) * 8];           \
    u16x8 pa1 = *(const u16x8*)&P16[q16 * 64 + ((4 + g) ^ qx7) * 8];           \
    __builtin_amdgcn_s_setprio(1);                                             \
    lsum = mfma16(pa0, onesv, lsum);     /* row-sum l, row-indexed */          \
    lsum = mfma16(pa1, onesv, lsum);                                           \
    _Pragma("unroll")                                                          \
    for (int dt = 0; dt < 4; dt++) {                                           \
      u16x8 vf0 = *(const u16x8*)&Vl[BUF][(dt * 16 + q16) * 64 +               \
                                          ((g)     ^ qx7) * 8];                \
      u16x8 vf1 = *(const u16x8*)&Vl[BUF][(dt * 16 + q16) * 64 +               \
                                          ((4 + g) ^ qx7) * 8];                \
      ctx[dt] = mfma16(pa0, vf0, ctx[dt]);                                     \
      ctx[dt] = mfma16(pa1, vf1, ctx[dt]);                                     \
    }                                                                          \
    __builtin_amdgcn_s_setprio(0);                                             \
  }

__global__ __launch_bounds__(256, 4) void attn_kernel(const u16* __restrict__ Qp,
                                                      const u16* __restrict__ Kp,
                                                      const u16* __restrict__ Vt,
                                                      u16* __restrict__ Ctx) {
  __shared__ u16 Kl[2][64 * 64];    // dbuf K tile [kv][d], chunk-XOR-swizzled
  __shared__ u16 Vl[2][64 * 64];    // dbuf V tile [d][token], same swizzle
  __shared__ u16 Pl[4][16 * 64];    // per-wave P, chunk-XOR-swizzled
  const int tid = threadIdx.x;
  const int lane = tid & 63, wv = tid >> 6;      // 4 waves
  const int q16 = lane & 15, g = lane >> 4;
  const int qx7 = q16 & 7;
  // XCD remap (assumes XCD = flat % 8): XCD owns 4 heads interleaved,
  // heavy q-chunks dispatch first.
  const int flat = blockIdx.x;                 // 0..1023
  const int xcd = flat & 7, idx = flat >> 3;   // idx 0..127
  const int bh = xcd * 4 + (idx & 3);
  const int qc = 31 - (idx >> 2);              // 0..31, heavy first
  const int bb = bh >> 4, h = bh & 15;
  const int qb16 = qc * 64 + wv * 16;          // this wave's 16-q base

  const u16* Qbase = Qp + (size_t)(h * MTOT + bb * S_LEN) * DH;
  const u16* Kbase = Kp + (size_t)(h * MTOT + bb * S_LEN) * DH;
  const u16* Vbase = Vt + (size_t)(h * DH) * MTOT + bb * S_LEN;
  u16* P16 = Pl[wv];

  // Q B-frags: b[j] = Q[q=lane&15][d = ds*32 + 8g + j]
  u16x8 qf[2];
#pragma unroll
  for (int ds = 0; ds < 2; ds++)
    qf[ds] = *(const u16x8*)&Qbase[(size_t)(qb16 + q16) * DH + ds * 32 + g * 8];

  f32x4 ctx[4] = {};
  f32x4 lsum = {};                   // row-sum of P (per q-row 4g+r)
  const u16x8 onesv = {0x3F80, 0x3F80, 0x3F80, 0x3F80,
                       0x3F80, 0x3F80, 0x3F80, 0x3F80};   // bf16 1.0 x8
  const int ntb = qc + 1;            // identical for all 4 waves

  // staging lane geometry: 8 rows x 8 chunks per gload; source chunk
  // pre-swizzled so LDS(r,c) = G(r, c ^ (r&7)) with LINEAR gload dest.
  const int srow = lane >> 3;                  // 0..7
  const int sc16 = (lane & 7) ^ srow;          // swizzled source chunk

  STAGE(0, 0);
  int cur = 0;
  for (int t = 0; t < ntb; ++t) {
    __syncthreads();                 // stage(t) landed; prev reads done
    if (t + 1 < ntb) STAGE(cur ^ 1, t + 1);
    TILE_BODY(cur, t);
    cur ^= 1;
  }

  float inv[4];
#pragma unroll
  for (int r = 0; r < 4; r++) inv[r] = 1.f / lsum[r];
#pragma unroll
  for (int dt = 0; dt < 4; dt++)
#pragma unroll
    for (int r = 0; r < 4; r++) {
      size_t grow = (size_t)(bb * S_LEN + qb16 + 4 * g + r) * DM + h * DH;
      Ctx[grow + dt * 16 + q16] = f2bf(ctx[dt][r] * inv[r]);
    }
}

// ---------------------------------------------------------------- launch
extern "C" void kernel_launch(void* const* d_in, const int* in_sizes, int n_in,
                              void* d_out, int out_size, void* d_ws, size_t ws_size,
                              hipStream_t stream) {
  const float* q_in = (const float*)d_in[0];
  const float* k_in = (const float*)d_in[1];
  const float* v_in = (const float*)d_in[2];
  // d_in[3] = causal mask, unused (causality structural)
  const float* wq = (const float*)d_in[4];
  const float* wk = (const float*)d_in[5];
  const float* wv = (const float*)d_in[6];
  const float* wo = (const float*)d_in[7];

  char* ws = (char*)d_ws;
  const size_t MB = 1024ull * 1024ull;
  u16* Qp  = (u16*)(ws + 0  * MB);
  u16* Kp  = (u16*)(ws + 8  * MB);
  u16* Vt  = (u16*)(ws + 16 * MB);
  u16* Ctx = (u16*)(ws + 24 * MB);
  u16* Wqb = (u16*)(ws + 56 * MB);
  u16* Wkb = (u16*)(ws + 58 * MB);
  u16* Wvb = (u16*)(ws + 60 * MB);
  u16* Wob = (u16*)(ws + 62 * MB);

  cvt_kernel<<<dim3(DM * DM / 1024, 4), 256, 0, stream>>>(
      wq, wk, wv, wo, Wqb, Wkb, Wvb, Wob);
  qkv_proj_kernel<<<dim3(8, MTOT / BM, 3), 256, 0, stream>>>(
      q_in, k_in, v_in, Wqb, Wkb, Wvb, Qp, Kp, Vt);
  attn_kernel<<<dim3(1024), 256, 0, stream>>>(Qp, Kp, Vt, Ctx);
  out_proj_kernel<<<dim3(8, MTOT / BM), 256, 0, stream>>>(Ctx, Wob, (float*)d_out);
}

// Round 19
// 107.062 us; speedup vs baseline: 1.0947x; 1.0947x over previous
//
#include <hip/hip_runtime.h>
#include <hip/hip_bf16.h>
#include <cstdint>

// MultiHeadAttention: out = ( softmax(causal((X Wq^T)(X Wk^T)^T / 8)) (X Wv^T) ) Wo^T
// B=2, S=2048, D_MODEL=1024, H=16, D_HEAD=64. All MFMA bf16, accum fp32.
//
// Round-19: R17 GEMM (fp32-A via global_load_lds, 48KB dbuf, 1 barrier/step
// — the 55us config) + ONLY the B-tile chunk-XOR swizzle that R18 proved
// (conflicts 4.7M -> 0). R18's reg-staged A is reverted: documented T14
// pitfall (reg-staging net-negative vs gload_lds on GEMM; qkv 55->83us).
// B layout was an 8-way bank conflict per ds_read_b128 (bank depends only
// on r16&1 and g); swizzle c^((row>>1)&3) spreads it to 2-way (free).
// attn (R17 fixed-shift softmax) and cvt unchanged.
//
// Workspace layout (64 MB):
//  [0,8M)    Qp  bf16 [16][4096][64]  per-head packed, pre-scaled by log2e/8
//  [8,16M)   Kp  bf16 [16][4096][64]  per-head packed
//  [16,24M)  Vt  bf16 [1024][4096]    V transposed (row = h*64+d, col = token)
//  [24,32M)  Ctx bf16 [4096][1024]
//  [56,64M)  Wq/Wk/Wv/Wo bf16 weights

typedef unsigned short u16;
typedef u16 u16x4 __attribute__((ext_vector_type(4)));
typedef u16 u16x8 __attribute__((ext_vector_type(8)));
typedef unsigned u32x2 __attribute__((ext_vector_type(2)));
typedef unsigned u32x4 __attribute__((ext_vector_type(4)));
typedef __bf16 bf16x8 __attribute__((ext_vector_type(8)));
typedef float f32x4 __attribute__((ext_vector_type(4)));

#define S_LEN 2048
#define DM 1024
#define NH 16
#define DH 64
#define BATCH 2
#define MTOT (BATCH*S_LEN)   // 4096

__device__ __forceinline__ u16 f2bf(float f) {
  union { float f; unsigned u; } v; v.f = f;
  unsigned r = v.u + 0x7FFFu + ((v.u >> 16) & 1u);   // RNE
  return (u16)(r >> 16);
}

__device__ __forceinline__ f32x4 mfma16(u16x8 a, u16x8 b, f32x4 c) {
  return __builtin_amdgcn_mfma_f32_16x16x32_bf16(
      __builtin_bit_cast(bf16x8, a), __builtin_bit_cast(bf16x8, b), c, 0, 0, 0);
}
__device__ __forceinline__ unsigned cvtpk_bf16(float lo, float hi) {
  unsigned r;
  asm("v_cvt_pk_bf16_f32 %0, %1, %2" : "=v"(r) : "v"(lo), "v"(hi));
  return r;
}
// async global -> LDS, 16B per lane; LDS dest = wave-uniform base + lane*16
__device__ __forceinline__ void gload16(const u16* g, u16* l) {
  __builtin_amdgcn_global_load_lds(
      (const __attribute__((address_space(1))) unsigned int*)g,
      (__attribute__((address_space(3))) unsigned int*)l, 16, 0, 0);
}

// ---------------------------------------------------------------- fp32->bf16
// Weights only (each weight is read 32x by its GEMM -> pre-convert pays;
// X tensors are read once -> consumed fp32 directly by the qkv GEMM).
__global__ __launch_bounds__(256) void cvt_kernel(
    const float* __restrict__ s0, const float* __restrict__ s1,
    const float* __restrict__ s2, const float* __restrict__ s3,
    u16* __restrict__ d0, u16* __restrict__ d1,
    u16* __restrict__ d2, u16* __restrict__ d3) {
  const int y = blockIdx.y;
  const float* s = (y == 0) ? s0 : (y == 1) ? s1 : (y == 2) ? s2 : s3;
  u16* d       = (y == 0) ? d0 : (y == 1) ? d1 : (y == 2) ? d2 : d3;
  int i = (blockIdx.x * 256 + threadIdx.x) * 4;
  f32x4 v = *(const f32x4*)&s[i];
  u16x4 o;
  o[0] = f2bf(v[0]); o[1] = f2bf(v[1]); o[2] = f2bf(v[2]); o[3] = f2bf(v[3]);
  *(u16x4*)&d[i] = o;
}

// ---------------------------------------------------------------- GEMM C=A*B^T
// 128x128 tile, BK=32, 4 waves (2x2), 4x4 16x16x32 MFMA.
// Double-buffered LDS, ONE barrier per K-step: prologue stage(buf0);
// loop { barrier; prefetch(buf^1, t+1); ds_read+MFMA from buf; swap }.
// AF32: A fp32 staged raw via gload_lds (16KB/buf, chunk-XOR-swizzled via
// pre-swizzled source), converted bf16 (v_cvt_pk_bf16_f32, RNE) at
// fragment-load time. B (and bf16-A): chunk-XOR swizzle c^((row>>1)&3)
// (R19: linear layout was an 8-way bank conflict on ds_read_b128).
#define BM 128
#define BN 128
#define BKK 32

template<int MODE, bool AF32>
__device__ __forceinline__ void gemm_core(const void* __restrict__ Av,
                                          const u16* __restrict__ Bw,
                                          void* __restrict__ Cv,
                                          int K, float scale,
                                          int bx, int by, u16* smem) {
  const int BUFSZ = AF32 ? 12288 : 8192;   // u16 per LDS buffer
  const int AOFF  = AF32 ? 8192  : 4096;   // u16 offset of B inside buffer
  const u16* A16 = (const u16*)Av;
  const float* A32 = (const float*)Av;
  const int tid  = threadIdx.x;
  const int lane = tid & 63, w = tid >> 6;
  const int g = lane >> 4, r16 = lane & 15;
  const int wm = w >> 1, wn = w & 1;
  const int rowBase = by * BM;
  const int colBase = bx * BN;
  f32x4 acc[4][4] = {};

  // B staging: gload_lds, source chunk pre-swizzled c^((row>>1)&3)
  const int srowB = lane >> 2;                            // 0..15
  const int swzB  = ((lane & 3) ^ ((lane >> 3) & 3)) * 8; // swizzled chunk *8u16
  const u16* gB[2]; int oB[2];
#pragma unroll
  for (int j = 0; j < 2; j++) {
    const int c = w * 2 + j;
    gB[j] = &Bw[(size_t)(colBase + c * 16 + srowB) * K + swzB];
    oB[j] = c * 512;
  }
  const u16* gA16[2]; int oA16[2];
  const float* gA32[4]; int oA32[4];
  if constexpr (AF32) {
    const int srow8 = lane >> 3;                       // 0..7
    const int scF   = ((lane & 7) ^ srow8) * 4;        // pre-swizzled src chunk
#pragma unroll
    for (int j = 0; j < 4; j++) {
      const int rb = w * 32 + j * 8;
      gA32[j] = &A32[(size_t)(rowBase + rb + srow8) * K + scF];
      oA32[j] = rb * 32;                               // float units
    }
  } else {
#pragma unroll
    for (int j = 0; j < 2; j++) {
      const int c = w * 2 + j;
      gA16[j] = &A16[(size_t)(rowBase + c * 16 + srowB) * K + swzB];
      oA16[j] = c * 512;
    }
  }

  const int NT = K / BKK;
  {
    u16* base = smem;
    if constexpr (AF32) {
      float* a32 = (float*)base;
#pragma unroll
      for (int j = 0; j < 4; j++) gload16((const u16*)gA32[j], (u16*)(a32 + oA32[j]));
    } else {
#pragma unroll
      for (int j = 0; j < 2; j++) gload16(gA16[j], base + oA16[j]);
    }
#pragma unroll
    for (int j = 0; j < 2; j++) gload16(gB[j], base + AOFF + oB[j]);
  }
  const int rswz = (r16 >> 1) & 3;
  int cur = 0;
  for (int t = 0; t < NT; ++t) {
    __syncthreads();               // stage(t) landed; buf^1 reads (t-1) done
    if (t + 1 < NT) {              // prefetch t+1: drained at NEXT barrier
      const int k0 = (t + 1) * BKK;
      u16* base = smem + (cur ^ 1) * BUFSZ;
      if constexpr (AF32) {
        float* a32 = (float*)base;
#pragma unroll
        for (int j = 0; j < 4; j++) gload16((const u16*)(gA32[j] + k0), (u16*)(a32 + oA32[j]));
      } else {
#pragma unroll
        for (int j = 0; j < 2; j++) gload16(gA16[j] + k0, base + oA16[j]);
      }
#pragma unroll
      for (int j = 0; j < 2; j++) gload16(gB[j] + k0, base + AOFF + oB[j]);
    }
    u16* As = smem + cur * BUFSZ;
    u16* Bs = As + AOFF;
    float* As32 = (float*)As;
    u16x8 af[4], bfv[4];
    if constexpr (AF32) {
      const int rx = r16 & 7;
#pragma unroll
      for (int i = 0; i < 4; i++) {
        const int base_ = (wm * 64 + i * 16 + r16) * 32;
        f32x4 a0 = *(const f32x4*)&As32[base_ + (((g * 2)     ^ rx) * 4)];
        f32x4 a1 = *(const f32x4*)&As32[base_ + (((g * 2 + 1) ^ rx) * 4)];
        u32x4 wv = {cvtpk_bf16(a0[0], a0[1]), cvtpk_bf16(a0[2], a0[3]),
                    cvtpk_bf16(a1[0], a1[1]), cvtpk_bf16(a1[2], a1[3])};
        af[i] = __builtin_bit_cast(u16x8, wv);
      }
    } else {
#pragma unroll
      for (int i = 0; i < 4; i++)
        af[i] = *(const u16x8*)&As[(wm*64 + i*16 + r16) * BKK + ((g ^ rswz) * 8)];
    }
#pragma unroll
    for (int j = 0; j < 4; j++)
      bfv[j] = *(const u16x8*)&Bs[(wn*64 + j*16 + r16) * BKK + ((g ^ rswz) * 8)];
    __builtin_amdgcn_s_setprio(1);
#pragma unroll
    for (int i = 0; i < 4; i++)
#pragma unroll
      for (int j = 0; j < 4; j++) acc[i][j] = mfma16(af[i], bfv[j], acc[i][j]);
    __builtin_amdgcn_s_setprio(0);
    cur ^= 1;
  }
  // C/D layout: col = lane&15, row = 4*(lane>>4)+reg
#pragma unroll
  for (int i = 0; i < 4; i++) {
#pragma unroll
    for (int j = 0; j < 4; j++) {
      int row = rowBase + wm*64 + i*16 + 4*g;
      int col = colBase + wn*64 + j*16 + r16;
      if (MODE == 0) {
        u16* O = (u16*)Cv;
        int head = col >> 6, d = col & 63;
#pragma unroll
        for (int r = 0; r < 4; r++)
          O[((size_t)head * MTOT + row + r) * DH + d] = f2bf(acc[i][j][r] * scale);
      } else if (MODE == 1) {
        u16x4 o;
#pragma unroll
        for (int r = 0; r < 4; r++) o[r] = f2bf(acc[i][j][r]);
        *(u16x4*)&((u16*)Cv)[(size_t)col * MTOT + row] = o;
      } else {
#pragma unroll
        for (int r = 0; r < 4; r++)
          ((float*)Cv)[(size_t)(row + r) * DM + col] = acc[i][j][r];
      }
    }
  }
}

// panel-locality remap: XCD x (dispatch = flat%8) owns row-panels x*4..x*4+3
// and ALL 8 columns of each -> every A panel fetched by exactly one XCD;
// per-XCD set = 2MB A(fp32) + 2MB W = L2-resident.
__device__ __forceinline__ void gemm_remap(int& bx, int& by) {
  const int flat = blockIdx.x + 8 * blockIdx.y;   // 0..255
  const int xcd = flat & 7, i = flat >> 3;        // i 0..31
  bx = i & 7;
  by = xcd * 4 + (i >> 3);
}

__global__ __launch_bounds__(256) void qkv_proj_kernel(
    const float* __restrict__ Xq, const float* __restrict__ Xk, const float* __restrict__ Xv,
    const u16* __restrict__ Wq, const u16* __restrict__ Wk, const u16* __restrict__ Wv,
    u16* __restrict__ Qp, u16* __restrict__ Kp, u16* __restrict__ Vt) {
  __shared__ u16 smem[24576];   // 48KB = 2 x (16KB A32 + 8KB B), all branches
  int bx, by; gemm_remap(bx, by);
  const int z = blockIdx.z;
  // Q pre-scaled by (1/sqrt(64)) * log2(e) -> softmax in exp2 domain
  if (z == 0)      gemm_core<0, true>(Xq, Wq, Qp, DM, 0.125f * 1.44269504f, bx, by, smem);
  else if (z == 1) gemm_core<0, true>(Xk, Wk, Kp, DM, 1.0f, bx, by, smem);
  else             gemm_core<1, true>(Xv, Wv, Vt, DM, 1.0f, bx, by, smem);
}

__global__ __launch_bounds__(256) void out_proj_kernel(
    const u16* __restrict__ Ctx, const u16* __restrict__ Wo, float* __restrict__ Out) {
  __shared__ u16 smem[16384];   // 32KB = 2 x 16KB
  int bx, by; gemm_remap(bx, by);
  gemm_core<2, false>(Ctx, Wo, Out, DM, 1.0f, bx, by, smem);
}

// ---------------------------------------------------------------- flash attn
// R9 structure + R17 fixed-shift softmax: 16 q-rows/wave, block = 64 q x
// 4 waves sharing dbuf-staged K/V LDS (32KB) + per-wave 2KB swizzled P
// buffer = 40KB. 1024 blocks, ntb = qc+1 uniform. Swapped QK^T (lane owns
// q-col), S accumulator INIT = -16 (fixed softmax shift, no max tracking),
// exp2 direct, l via mfma(P, ones) row-indexed. T5 setprio, chunk-XOR
// swizzle via pre-swizzled gload source.

#define STAGE(B, T)                                                            \
  {                                                                            \
    const int kv0_ = (T) * 64;                                                 \
    _Pragma("unroll")                                                          \
    for (int j = 0; j < 2; j++) {                                              \
      const int rb = wv * 16 + j * 8;                                          \
      gload16(&Kbase[(size_t)(kv0_ + rb + srow) * DH + sc16 * 8],              \
              &Kl[B][rb * 64]);                                                \
      gload16(&Vbase[(size_t)(rb + srow) * MTOT + kv0_ + sc16 * 8],            \
              &Vl[B][rb * 64]);                                                \
    }                                                                          \
  }

#define TILE_BODY(BUF, T)                                                      \
  {                                                                            \
    const int kv0 = (T) * 64;                                                  \
    const f32x4 minit = {-16.f, -16.f, -16.f, -16.f};                          \
    f32x4 s[4] = {minit, minit, minit, minit};   /* C-in = fixed shift */      \
    __builtin_amdgcn_s_setprio(1);                                             \
    _Pragma("unroll")                                                          \
    for (int f = 0; f < 4; f++) {                                              \
      _Pragma("unroll")                                                        \
      for (int ds = 0; ds < 2; ds++) {                                         \
        u16x8 kf = *(const u16x8*)&Kl[BUF][(f * 16 + q16) * 64 +               \
                                           ((ds * 4 + g) ^ qx7) * 8];          \
        s[f] = mfma16(kf, qf[ds], s[f]);                                       \
      }                                                                        \
    }                                                                          \
    __builtin_amdgcn_s_setprio(0);                                             \
    if ((T) == ntb - 1) {      /* only last tile crosses the diagonal */       \
      const int qg = qb16 + q16;                                               \
      _Pragma("unroll")                                                        \
      for (int f = 0; f < 4; f++)                                              \
        _Pragma("unroll")                                                      \
        for (int r = 0; r < 4; r++)                                            \
          if (kv0 + f * 16 + 4 * g + r > qg) s[f][r] = -1e30f;                 \
    }                                                                          \
    _Pragma("unroll")                                                          \
    for (int f = 0; f < 4; f++)                                                \
      _Pragma("unroll")                                                        \
      for (int r = 0; r < 4; r++) s[f][r] = exp2f(s[f][r]);                    \
    /* P (16q x 64kv) -> per-wave swizzled LDS, then read as A-frags */        \
    _Pragma("unroll")                                                          \
    for (int f = 0; f < 4; f++) {                                              \
      const int cidx = (((2 * f + (g >> 1)) ^ qx7) * 8) + 4 * (g & 1);         \
      u32x2 pw = {cvtpk_bf16(s[f][0], s[f][1]), cvtpk_bf16(s[f][2], s[f][3])}; \
      *(u32x2*)&P16[q16 * 64 + cidx] = pw;                                     \
    }                                                                          \
    asm volatile("s_waitcnt lgkmcnt(0)" ::: "memory");                         \
    __builtin_amdgcn_sched_barrier(0);                                         \
    u16x8 pa0 = *(const u16x8*)&P16[q16 * 64 + ((g)     ^ qx7) * 8];           \
    u16x8 pa1 = *(const u16x8*)&P16[q16 * 64 + ((4 + g) ^ qx7) * 8];           \
    __builtin_amdgcn_s_setprio(1);                                             \
    lsum = mfma16(pa0, onesv, lsum);     /* row-sum l, row-indexed */          \
    lsum = mfma16(pa1, onesv, lsum);                                           \
    _Pragma("unroll")                                                          \
    for (int dt = 0; dt < 4; dt++) {                                           \
      u16x8 vf0 = *(const u16x8*)&Vl[BUF][(dt * 16 + q16) * 64 +               \
                                          ((g)     ^ qx7) * 8];                \
      u16x8 vf1 = *(const u16x8*)&Vl[BUF][(dt * 16 + q16) * 64 +               \
                                          ((4 + g) ^ qx7) * 8];                \
      ctx[dt] = mfma16(pa0, vf0, ctx[dt]);                                     \
      ctx[dt] = mfma16(pa1, vf1, ctx[dt]);                                     \
    }                                                                          \
    __builtin_amdgcn_s_setprio(0);                                             \
  }

__global__ __launch_bounds__(256, 4) void attn_kernel(const u16* __restrict__ Qp,
                                                      const u16* __restrict__ Kp,
                                                      const u16* __restrict__ Vt,
                                                      u16* __restrict__ Ctx) {
  __shared__ u16 Kl[2][64 * 64];    // dbuf K tile [kv][d], chunk-XOR-swizzled
  __shared__ u16 Vl[2][64 * 64];    // dbuf V tile [d][token], same swizzle
  __shared__ u16 Pl[4][16 * 64];    // per-wave P, chunk-XOR-swizzled
  const int tid = threadIdx.x;
  const int lane = tid & 63, wv = tid >> 6;      // 4 waves
  const int q16 = lane & 15, g = lane >> 4;
  const int qx7 = q16 & 7;
  // XCD remap (assumes XCD = flat % 8): XCD owns 4 heads interleaved,
  // heavy q-chunks dispatch first.
  const int flat = blockIdx.x;                 // 0..1023
  const int xcd = flat & 7, idx = flat >> 3;   // idx 0..127
  const int bh = xcd * 4 + (idx & 3);
  const int qc = 31 - (idx >> 2);              // 0..31, heavy first
  const int bb = bh >> 4, h = bh & 15;
  const int qb16 = qc * 64 + wv * 16;          // this wave's 16-q base

  const u16* Qbase = Qp + (size_t)(h * MTOT + bb * S_LEN) * DH;
  const u16* Kbase = Kp + (size_t)(h * MTOT + bb * S_LEN) * DH;
  const u16* Vbase = Vt + (size_t)(h * DH) * MTOT + bb * S_LEN;
  u16* P16 = Pl[wv];

  // Q B-frags: b[j] = Q[q=lane&15][d = ds*32 + 8g + j]
  u16x8 qf[2];
#pragma unroll
  for (int ds = 0; ds < 2; ds++)
    qf[ds] = *(const u16x8*)&Qbase[(size_t)(qb16 + q16) * DH + ds * 32 + g * 8];

  f32x4 ctx[4] = {};
  f32x4 lsum = {};                   // row-sum of P (per q-row 4g+r)
  const u16x8 onesv = {0x3F80, 0x3F80, 0x3F80, 0x3F80,
                       0x3F80, 0x3F80, 0x3F80, 0x3F80};   // bf16 1.0 x8
  const int ntb = qc + 1;            // identical for all 4 waves

  // staging lane geometry: 8 rows x 8 chunks per gload; source chunk
  // pre-swizzled so LDS(r,c) = G(r, c ^ (r&7)) with LINEAR gload dest.
  const int srow = lane >> 3;                  // 0..7
  const int sc16 = (lane & 7) ^ srow;          // swizzled source chunk

  STAGE(0, 0);
  int cur = 0;
  for (int t = 0; t < ntb; ++t) {
    __syncthreads();                 // stage(t) landed; prev reads done
    if (t + 1 < ntb) STAGE(cur ^ 1, t + 1);
    TILE_BODY(cur, t);
    cur ^= 1;
  }

  float inv[4];
#pragma unroll
  for (int r = 0; r < 4; r++) inv[r] = 1.f / lsum[r];
#pragma unroll
  for (int dt = 0; dt < 4; dt++)
#pragma unroll
    for (int r = 0; r < 4; r++) {
      size_t grow = (size_t)(bb * S_LEN + qb16 + 4 * g + r) * DM + h * DH;
      Ctx[grow + dt * 16 + q16] = f2bf(ctx[dt][r] * inv[r]);
    }
}

// ---------------------------------------------------------------- launch
extern "C" void kernel_launch(void* const* d_in, const int* in_sizes, int n_in,
                              void* d_out, int out_size, void* d_ws, size_t ws_size,
                              hipStream_t stream) {
  const float* q_in = (const float*)d_in[0];
  const float* k_in = (const float*)d_in[1];
  const float* v_in = (const float*)d_in[2];
  // d_in[3] = causal mask, unused (causality structural)
  const float* wq = (const float*)d_in[4];
  const float* wk = (const float*)d_in[5];
  const float* wv = (const float*)d_in[6];
  const float* wo = (const float*)d_in[7];

  char* ws = (char*)d_ws;
  const size_t MB = 1024ull * 1024ull;
  u16* Qp  = (u16*)(ws + 0  * MB);
  u16* Kp  = (u16*)(ws + 8  * MB);
  u16* Vt  = (u16*)(ws + 16 * MB);
  u16* Ctx = (u16*)(ws + 24 * MB);
  u16* Wqb = (u16*)(ws + 56 * MB);
  u16* Wkb = (u16*)(ws + 58 * MB);
  u16* Wvb = (u16*)(ws + 60 * MB);
  u16* Wob = (u16*)(ws + 62 * MB);

  cvt_kernel<<<dim3(DM * DM / 1024, 4), 256, 0, stream>>>(
      wq, wk, wv, wo, Wqb, Wkb, Wvb, Wob);
  qkv_proj_kernel<<<dim3(8, MTOT / BM, 3), 256, 0, stream>>>(
      q_in, k_in, v_in, Wqb, Wkb, Wvb, Qp, Kp, Vt);
  attn_kernel<<<dim3(1024), 256, 0, stream>>>(Qp, Kp, Vt, Ctx);
  out_proj_kernel<<<dim3(8, MTOT / BM), 256, 0, stream>>>(Ctx, Wob, (float*)d_out);
}